// Round 1
// baseline (2999.189 us; speedup 1.0000x reference)
//
#include <hip/hip_runtime.h>

#define DEV __device__ __forceinline__

typedef __attribute__((ext_vector_type(8))) __bf16 bf16x8;
typedef __attribute__((ext_vector_type(4))) float f32x4;

DEV unsigned short f2bf(float f) {
  unsigned int u = __float_as_uint(f);
  u += 0x7FFFu + ((u >> 16) & 1u);   // RNE
  return (unsigned short)(u >> 16);
}

// ---------------- kernel 1: f32 -> bf16 (vectorized) ----------------
__global__ __launch_bounds__(256) void k_f32_to_bf16(const float* __restrict__ x,
                                                     unsigned short* __restrict__ y) {
  size_t i = ((size_t)blockIdx.x * 256 + threadIdx.x) * 8;
  float4 a = *(const float4*)(x + i);
  float4 b = *(const float4*)(x + i + 4);
  union { unsigned short u[8]; uint4 v; } o;
  o.u[0] = f2bf(a.x); o.u[1] = f2bf(a.y); o.u[2] = f2bf(a.z); o.u[3] = f2bf(a.w);
  o.u[4] = f2bf(b.x); o.u[5] = f2bf(b.y); o.u[6] = f2bf(b.z); o.u[7] = f2bf(b.w);
  *(uint4*)(y + i) = o.v;
}

// ------- kernel 2: AWQ int4 dequant -> W^T bf16 [N][K] (LDS transpose) -------
// qw: [K][N/8] int32 (sequential nibbles), qz: [K/128][N/8], sc: [K/128][N] f32
__global__ __launch_bounds__(256) void k_dequant_t(const int* __restrict__ qw,
                                                   const int* __restrict__ qz,
                                                   const float* __restrict__ sc,
                                                   unsigned short* __restrict__ wt,
                                                   int K, int N) {
  __shared__ __align__(16) unsigned short st[64][72];  // 64 n-rows x 64 k (+8 pad)
  const int k0 = blockIdx.x * 64, n0 = blockIdx.y * 64;
  const int t = threadIdx.x;
  const int g = k0 >> 7;            // group constant per 64-row tile (gs=128)
  const int Np = N >> 3;
#pragma unroll
  for (int it = 0; it < 2; ++it) {
    int idx = t + it * 256;         // 0..511 -> 64 k x 8 int32 cols
    int k = idx >> 3;
    int nc = idx & 7;
    unsigned int w = (unsigned int)qw[(size_t)(k0 + k) * Np + (n0 >> 3) + nc];
    unsigned int z = (unsigned int)qz[(size_t)g * Np + (n0 >> 3) + nc];
#pragma unroll
    for (int i = 0; i < 8; ++i) {
      float s = sc[(size_t)g * N + n0 + nc * 8 + i];
      float v = ((float)(int)((w >> (4 * i)) & 0xFu) -
                 (float)(int)((z >> (4 * i)) & 0xFu)) * s;
      st[nc * 8 + i][k] = f2bf(v);
    }
  }
  __syncthreads();
  // coalesced write-out: 4 threads per n-row, 16 elems (32B) each
  const int n = t >> 2, c = t & 3;
  uint4 v0 = *(const uint4*)&st[n][c * 16];
  uint4 v1 = *(const uint4*)&st[n][c * 16 + 8];
  unsigned short* dst = wt + (size_t)(n0 + n) * K + k0 + c * 16;
  *(uint4*)dst = v0;
  *(uint4*)(dst + 8) = v1;
}

// ---------------- kernel 3: GEMM  C[M][N] = A[M][K] * B^T ( B given [N][K] ) ----
// 128x128 tile, BK=64, 256 threads (4 waves, each 64x64 out = 4x4 frags 16x16).
// Staging: global_load_lds 16B with pre-swizzled source (slot ^= row&7) so the
// linear LDS dest is XOR-swizzled -> conflict-free ds_read_b128 fragment reads.
template <int GELU>
__global__ __launch_bounds__(256) void k_gemm_bt(const unsigned short* __restrict__ A,
                                                 const unsigned short* __restrict__ B,
                                                 void* __restrict__ C,
                                                 int M, int N, int K) {
  __shared__ __align__(16) unsigned short sA[128 * 64];
  __shared__ __align__(16) unsigned short sB[128 * 64];
  const int tid = threadIdx.x;
  const int lane = tid & 63;
  const int wave = tid >> 6;
  const int n0 = blockIdx.x * 128;
  const int m0 = blockIdx.y * 128;

  const int l8 = lane >> 3;              // row-within-8
  const int slotg = (lane & 7) ^ l8;     // pre-swizzled global 16B slot

  f32x4 acc[4][4] = {};

  const int r16 = lane & 15;
  const int q = lane >> 4;

  for (int kt = 0; kt < K; kt += 64) {
#pragma unroll
    for (int j = 0; j < 4; ++j) {
      int c = wave * 4 + j;              // 1KB chunk id (16 total)
      int row = c * 8 + l8;              // tile row 0..127
      const unsigned short* ga = A + (size_t)(m0 + row) * K + kt + slotg * 8;
      const unsigned short* gb = B + (size_t)(n0 + row) * K + kt + slotg * 8;
      __builtin_amdgcn_global_load_lds((const __attribute__((address_space(1))) void*)ga,
                                       (__attribute__((address_space(3))) void*)(sA + c * 512),
                                       16, 0, 0);
      __builtin_amdgcn_global_load_lds((const __attribute__((address_space(1))) void*)gb,
                                       (__attribute__((address_space(3))) void*)(sB + c * 512),
                                       16, 0, 0);
    }
    __syncthreads();   // drains vmcnt -> LDS tiles ready
#pragma unroll
    for (int kk = 0; kk < 2; ++kk) {
      bf16x8 af[4], bb[4];
      const int kbyte = kk * 64 + q * 16;
#pragma unroll
      for (int f = 0; f < 4; ++f) {
        int ar = (wave >> 1) * 64 + f * 16 + r16;
        af[f] = *(const bf16x8*)((const char*)sA + (ar * 128 + (kbyte ^ ((ar & 7) << 4))));
        int br = (wave & 1) * 64 + f * 16 + r16;
        bb[f] = *(const bf16x8*)((const char*)sB + (br * 128 + (kbyte ^ ((br & 7) << 4))));
      }
#pragma unroll
      for (int i = 0; i < 4; ++i)
#pragma unroll
        for (int jn = 0; jn < 4; ++jn)
          acc[i][jn] = __builtin_amdgcn_mfma_f32_16x16x32_bf16(af[i], bb[jn], acc[i][jn], 0, 0, 0);
    }
    __syncthreads();   // compute done before next-tile overwrite
  }

  // epilogue: C/D layout col=lane&15, row=(lane>>4)*4+reg  [m89-verified]
  const int mb = m0 + (wave >> 1) * 64 + q * 4;
  const int nb = n0 + (wave & 1) * 64 + r16;
#pragma unroll
  for (int i = 0; i < 4; ++i) {
#pragma unroll
    for (int jn = 0; jn < 4; ++jn) {
#pragma unroll
      for (int r = 0; r < 4; ++r) {
        int row = mb + i * 16 + r;
        int col = nb + jn * 16;
        float v = acc[i][jn][r];
        if (GELU) {
          v = 0.5f * v * (1.0f + erff(v * 0.70710678118654752440f));  // exact gelu
          ((unsigned short*)C)[(size_t)row * N + col] = f2bf(v);
        } else {
          ((float*)C)[(size_t)row * N + col] = v;
        }
      }
    }
  }
}

extern "C" void kernel_launch(void* const* d_in, const int* in_sizes, int n_in,
                              void* d_out, int out_size, void* d_ws, size_t ws_size,
                              hipStream_t stream) {
  const float* x  = (const float*)d_in[0];
  const int* uqw  = (const int*)d_in[1];
  const int* uqz  = (const int*)d_in[2];
  const float* usc = (const float*)d_in[3];
  const int* dqw  = (const int*)d_in[4];
  const int* dqz  = (const int*)d_in[5];
  const float* dsc = (const float*)d_in[6];
  float* out = (float*)d_out;

  const int T = 8192, D = 4096, F = 16384;
  char* ws = (char*)d_ws;
  unsigned short* xb = (unsigned short*)ws;                                  // 64 MiB
  unsigned short* h  = (unsigned short*)(ws + (size_t)T * D * 2);            // 256 MiB
  unsigned short* wt = (unsigned short*)(ws + (size_t)T * D * 2 + (size_t)T * F * 2); // 128 MiB

  // 1) x -> bf16
  k_f32_to_bf16<<<dim3((T * D) / (256 * 8)), 256, 0, stream>>>(x, xb);
  // 2) dequant W_up -> W^T [F][D]
  k_dequant_t<<<dim3(D / 64, F / 64), 256, 0, stream>>>(uqw, uqz, usc, wt, D, F);
  // 3) h = gelu(x @ W_up)  (bf16)
  k_gemm_bt<1><<<dim3(F / 128, T / 128), 256, 0, stream>>>(xb, wt, (void*)h, T, F, D);
  // 4) dequant W_down -> W^T [D][F] (reuse buffer)
  k_dequant_t<<<dim3(F / 64, D / 64), 256, 0, stream>>>(dqw, dqz, dsc, wt, F, D);
  // 5) out = h @ W_down  (f32)
  k_gemm_bt<0><<<dim3(D / 128, T / 128), 256, 0, stream>>>(h, wt, (void*)out, T, D, F);
}

// Round 2
// 2833.673 us; speedup vs baseline: 1.0584x; 1.0584x over previous
//
#include <hip/hip_runtime.h>

typedef __attribute__((ext_vector_type(8))) __bf16 bf16x8;
typedef __attribute__((ext_vector_type(4))) float f32x4;

#define DEV __device__ __forceinline__

DEV unsigned short f2bf(float f) {
  unsigned int u = __float_as_uint(f);
  u += 0x7FFFu + ((u >> 16) & 1u);   // RNE
  return (unsigned short)(u >> 16);
}

// ---------------- kernel 1: f32 -> bf16 (vectorized) ----------------
__global__ __launch_bounds__(256) void k_f32_to_bf16(const float* __restrict__ x,
                                                     unsigned short* __restrict__ y) {
  size_t i = ((size_t)blockIdx.x * 256 + threadIdx.x) * 8;
  float4 a = *(const float4*)(x + i);
  float4 b = *(const float4*)(x + i + 4);
  union { unsigned short u[8]; uint4 v; } o;
  o.u[0] = f2bf(a.x); o.u[1] = f2bf(a.y); o.u[2] = f2bf(a.z); o.u[3] = f2bf(a.w);
  o.u[4] = f2bf(b.x); o.u[5] = f2bf(b.y); o.u[6] = f2bf(b.z); o.u[7] = f2bf(b.w);
  *(uint4*)(y + i) = o.v;
}

// ------- kernel 2: AWQ int4 dequant -> W^T bf16 [N][K] (LDS transpose) -------
__global__ __launch_bounds__(256) void k_dequant_t(const int* __restrict__ qw,
                                                   const int* __restrict__ qz,
                                                   const float* __restrict__ sc,
                                                   unsigned short* __restrict__ wt,
                                                   int K, int N) {
  __shared__ __align__(16) unsigned short st[64][72];
  const int k0 = blockIdx.x * 64, n0 = blockIdx.y * 64;
  const int t = threadIdx.x;
  const int g = k0 >> 7;
  const int Np = N >> 3;
#pragma unroll
  for (int it = 0; it < 2; ++it) {
    int idx = t + it * 256;
    int k = idx >> 3;
    int nc = idx & 7;
    unsigned int w = (unsigned int)qw[(size_t)(k0 + k) * Np + (n0 >> 3) + nc];
    unsigned int z = (unsigned int)qz[(size_t)g * Np + (n0 >> 3) + nc];
#pragma unroll
    for (int i = 0; i < 8; ++i) {
      float s = sc[(size_t)g * N + n0 + nc * 8 + i];
      float v = ((float)(int)((w >> (4 * i)) & 0xFu) -
                 (float)(int)((z >> (4 * i)) & 0xFu)) * s;
      st[nc * 8 + i][k] = f2bf(v);
    }
  }
  __syncthreads();
  const int n = t >> 2, c = t & 3;
  uint4 v0 = *(const uint4*)&st[n][c * 16];
  uint4 v1 = *(const uint4*)&st[n][c * 16 + 8];
  unsigned short* dst = wt + (size_t)(n0 + n) * K + k0 + c * 16;
  *(uint4*)dst = v0;
  *(uint4*)(dst + 8) = v1;
}

// ---------------- kernel 3: 256x256 8-phase GEMM  C = A[M][K] * B^T([N][K]) ----
// 512 threads = 8 waves (2 M x 4 N), per-wave out 128x64 (acc[8][4] of 16x16).
// LDS: A,B rings of 4 K-slabs (256 rows x 32 k bf16 = 16KB each) = 128 KiB.
// Per phase: {ds_read frags, stage 1 half-tile (2x global_load_lds 16B),
//   s_barrier, setprio(1), 16 MFMA, setprio(0), s_barrier}. Counted vmcnt(4)
// only at K-tile boundaries (vmcnt(0) in the last two tiles' tails).
// Swizzle: 16B slot ^= (row>>1)&3 applied on BOTH pre-swizzled global source
// and ds_read address (rule #21); 2 lanes/bank-group => conflict-free.

#define STAGE_A(h) do { const unsigned short* g_ = A + gsA + (size_t)(h) * 32;               \
  __builtin_amdgcn_global_load_lds((const __attribute__((address_space(1))) void*)g_,        \
      (__attribute__((address_space(3))) void*)(&sA[(h) & 3][0] + tid * 8), 16, 0, 0);       \
  __builtin_amdgcn_global_load_lds((const __attribute__((address_space(1))) void*)(g_ + (size_t)128 * K), \
      (__attribute__((address_space(3))) void*)(&sA[(h) & 3][4096] + tid * 8), 16, 0, 0); } while (0)
#define STAGE_B(h) do { const unsigned short* g_ = B + gsB + (size_t)(h) * 32;               \
  __builtin_amdgcn_global_load_lds((const __attribute__((address_space(1))) void*)g_,        \
      (__attribute__((address_space(3))) void*)(&sB[(h) & 3][0] + tid * 8), 16, 0, 0);       \
  __builtin_amdgcn_global_load_lds((const __attribute__((address_space(1))) void*)(g_ + (size_t)128 * K), \
      (__attribute__((address_space(3))) void*)(&sB[(h) & 3][4096] + tid * 8), 16, 0, 0); } while (0)

#define LDA(s, m) (*(const bf16x8*)((const char*)&sA[s][0] + offA + (m) * 1024))
#define LDB(s, n) (*(const bf16x8*)((const char*)&sB[s][0] + offB + (n) * 1024))

template <int GELU>
__global__ __launch_bounds__(512, 2) void k_gemm256(const unsigned short* __restrict__ A,
                                                    const unsigned short* __restrict__ B,
                                                    void* __restrict__ C,
                                                    int M, int N, int K) {
  __shared__ __align__(16) unsigned short sA[4][8192];
  __shared__ __align__(16) unsigned short sB[4][8192];
  const int tid = threadIdx.x;
  const int lane = tid & 63;
  const int wave = tid >> 6;
  const int wm = wave >> 2, wn = wave & 3;
  const int r16 = lane & 15, q = lane >> 4;

  // XCD-aware block swizzle (grid % 8 == 0 for both GEMMs)
  const int nbx = N >> 8;
  const int cpx = gridDim.x >> 3;
  const int sw = (blockIdx.x & 7) * cpx + (blockIdx.x >> 3);
  const int m0 = (sw / nbx) * 256;
  const int n0 = (sw % nbx) * 256;

  const int rA = wm * 128 + r16;
  const int rB = wn * 64 + r16;
  const int offA = rA * 64 + ((q * 16) ^ (((rA >> 1) & 3) << 4));
  const int offB = rB * 64 + ((q * 16) ^ (((rB >> 1) & 3) << 4));

  const int sr = tid >> 2;                        // staging row (0..127)
  const int ssrc = (tid & 3) ^ ((sr >> 1) & 3);   // pre-swizzled global 16B slot
  const size_t gsA = (size_t)(m0 + sr) * K + (size_t)ssrc * 8;
  const size_t gsB = (size_t)(n0 + sr) * K + (size_t)ssrc * 8;

  f32x4 acc[8][4] = {};
  const int NT = K >> 6;

  // prologue: slabs 0,1,2 (A+B); guarantee 0,1 resident, slab 2 in flight
  STAGE_A(0); STAGE_B(0); STAGE_A(1); STAGE_B(1); STAGE_A(2); STAGE_B(2);
  asm volatile("s_waitcnt vmcnt(4)" ::: "memory");
  __builtin_amdgcn_s_barrier();

  for (int t = 0; t < NT; ++t) {
    const int s0 = (2 * t) & 3, s1 = (2 * t + 1) & 3;
    const int h3 = 2 * t + 3, h4 = 2 * t + 4;
    bf16x8 af[4], bf[4];

    // ---- phase 1: kk0, m0-3 (8 ds_reads) ; stage A(2t+3)
#pragma unroll
    for (int i = 0; i < 4; ++i) af[i] = LDA(s0, i);
#pragma unroll
    for (int j = 0; j < 4; ++j) bf[j] = LDB(s0, j);
    if (h3 < 2 * NT) STAGE_A(h3);
    __builtin_amdgcn_s_barrier();
    __builtin_amdgcn_s_setprio(1);
#pragma unroll
    for (int i = 0; i < 4; ++i)
#pragma unroll
      for (int j = 0; j < 4; ++j)
        acc[i][j] = __builtin_amdgcn_mfma_f32_16x16x32_bf16(af[i], bf[j], acc[i][j], 0, 0, 0);
    __builtin_amdgcn_s_setprio(0);
    __builtin_amdgcn_s_barrier();

    // ---- phase 2: kk0, m4-7 (4 ds_reads, B reused) ; stage B(2t+3)
#pragma unroll
    for (int i = 0; i < 4; ++i) af[i] = LDA(s0, 4 + i);
    if (h3 < 2 * NT) STAGE_B(h3);
    __builtin_amdgcn_s_barrier();
    __builtin_amdgcn_s_setprio(1);
#pragma unroll
    for (int i = 0; i < 4; ++i)
#pragma unroll
      for (int j = 0; j < 4; ++j)
        acc[4 + i][j] = __builtin_amdgcn_mfma_f32_16x16x32_bf16(af[i], bf[j], acc[4 + i][j], 0, 0, 0);
    __builtin_amdgcn_s_setprio(0);
    __builtin_amdgcn_s_barrier();

    // ---- phase 3: kk1, m0-3 (8 ds_reads) ; stage A(2t+4)
#pragma unroll
    for (int i = 0; i < 4; ++i) af[i] = LDA(s1, i);
#pragma unroll
    for (int j = 0; j < 4; ++j) bf[j] = LDB(s1, j);
    if (h4 < 2 * NT) STAGE_A(h4);
    __builtin_amdgcn_s_barrier();
    __builtin_amdgcn_s_setprio(1);
#pragma unroll
    for (int i = 0; i < 4; ++i)
#pragma unroll
      for (int j = 0; j < 4; ++j)
        acc[i][j] = __builtin_amdgcn_mfma_f32_16x16x32_bf16(af[i], bf[j], acc[i][j], 0, 0, 0);
    __builtin_amdgcn_s_setprio(0);
    __builtin_amdgcn_s_barrier();

    // ---- phase 4: kk1, m4-7 (4 ds_reads) ; stage B(2t+4) ; boundary vmcnt
#pragma unroll
    for (int i = 0; i < 4; ++i) af[i] = LDA(s1, 4 + i);
    if (h4 < 2 * NT) STAGE_B(h4);
    __builtin_amdgcn_s_barrier();
    __builtin_amdgcn_s_setprio(1);
#pragma unroll
    for (int i = 0; i < 4; ++i)
#pragma unroll
      for (int j = 0; j < 4; ++j)
        acc[4 + i][j] = __builtin_amdgcn_mfma_f32_16x16x32_bf16(af[i], bf[j], acc[4 + i][j], 0, 0, 0);
    __builtin_amdgcn_s_setprio(0);
    if (t < NT - 2) { asm volatile("s_waitcnt vmcnt(4)" ::: "memory"); }
    else            { asm volatile("s_waitcnt vmcnt(0)" ::: "memory"); }
    __builtin_amdgcn_s_barrier();
  }

  // epilogue: C/D layout col=lane&15, row=(lane>>4)*4+reg
  const int mb = m0 + wm * 128 + q * 4;
  const int nb = n0 + wn * 64 + r16;
#pragma unroll
  for (int i = 0; i < 8; ++i) {
#pragma unroll
    for (int j = 0; j < 4; ++j) {
#pragma unroll
      for (int r = 0; r < 4; ++r) {
        int row = mb + i * 16 + r;
        int col = nb + j * 16;
        float v = acc[i][j][r];
        if (GELU) {
          v = 0.5f * v * (1.0f + erff(v * 0.70710678118654752440f));
          ((unsigned short*)C)[(size_t)row * N + col] = f2bf(v);
        } else {
          ((float*)C)[(size_t)row * N + col] = v;
        }
      }
    }
  }
}

extern "C" void kernel_launch(void* const* d_in, const int* in_sizes, int n_in,
                              void* d_out, int out_size, void* d_ws, size_t ws_size,
                              hipStream_t stream) {
  const float* x  = (const float*)d_in[0];
  const int* uqw  = (const int*)d_in[1];
  const int* uqz  = (const int*)d_in[2];
  const float* usc = (const float*)d_in[3];
  const int* dqw  = (const int*)d_in[4];
  const int* dqz  = (const int*)d_in[5];
  const float* dsc = (const float*)d_in[6];
  float* out = (float*)d_out;

  const int T = 8192, D = 4096, F = 16384;
  char* ws = (char*)d_ws;
  unsigned short* xb = (unsigned short*)ws;                                  // 64 MiB
  unsigned short* h  = (unsigned short*)(ws + (size_t)T * D * 2);            // 256 MiB
  unsigned short* wt = (unsigned short*)(ws + (size_t)T * D * 2 + (size_t)T * F * 2); // 128 MiB

  k_f32_to_bf16<<<dim3((T * D) / (256 * 8)), 256, 0, stream>>>(x, xb);
  k_dequant_t<<<dim3(D / 64, F / 64), 256, 0, stream>>>(uqw, uqz, usc, wt, D, F);
  k_gemm256<1><<<dim3((T / 256) * (F / 256)), 512, 0, stream>>>(xb, wt, (void*)h, T, F, D);
  k_dequant_t<<<dim3(F / 64, D / 64), 256, 0, stream>>>(dqw, dqz, dsc, wt, F, D);
  k_gemm256<0><<<dim3((T / 256) * (D / 256)), 512, 0, stream>>>(h, wt, (void*)out, T, D, F);
}

// Round 3
// 2622.775 us; speedup vs baseline: 1.1435x; 1.0804x over previous
//
#include <hip/hip_runtime.h>

typedef __attribute__((ext_vector_type(8))) __bf16 bf16x8;
typedef __attribute__((ext_vector_type(4))) float f32x4;

#define DEV __device__ __forceinline__

DEV unsigned short f2bf(float f) {
  unsigned int u = __float_as_uint(f);
  u += 0x7FFFu + ((u >> 16) & 1u);   // RNE
  return (unsigned short)(u >> 16);
}

// ---------------- kernel 1: f32 -> bf16 (vectorized) ----------------
__global__ __launch_bounds__(256) void k_f32_to_bf16(const float* __restrict__ x,
                                                     unsigned short* __restrict__ y) {
  size_t i = ((size_t)blockIdx.x * 256 + threadIdx.x) * 8;
  float4 a = *(const float4*)(x + i);
  float4 b = *(const float4*)(x + i + 4);
  union { unsigned short u[8]; uint4 v; } o;
  o.u[0] = f2bf(a.x); o.u[1] = f2bf(a.y); o.u[2] = f2bf(a.z); o.u[3] = f2bf(a.w);
  o.u[4] = f2bf(b.x); o.u[5] = f2bf(b.y); o.u[6] = f2bf(b.z); o.u[7] = f2bf(b.w);
  *(uint4*)(y + i) = o.v;
}

// ------- kernel 2: AWQ int4 dequant -> W^T bf16 [N][K] (LDS transpose) -------
__global__ __launch_bounds__(256) void k_dequant_t(const int* __restrict__ qw,
                                                   const int* __restrict__ qz,
                                                   const float* __restrict__ sc,
                                                   unsigned short* __restrict__ wt,
                                                   int K, int N) {
  __shared__ __align__(16) unsigned short st[64][72];
  const int k0 = blockIdx.x * 64, n0 = blockIdx.y * 64;
  const int t = threadIdx.x;
  const int g = k0 >> 7;
  const int Np = N >> 3;
#pragma unroll
  for (int it = 0; it < 2; ++it) {
    int idx = t + it * 256;
    int k = idx >> 3;
    int nc = idx & 7;
    unsigned int w = (unsigned int)qw[(size_t)(k0 + k) * Np + (n0 >> 3) + nc];
    unsigned int z = (unsigned int)qz[(size_t)g * Np + (n0 >> 3) + nc];
#pragma unroll
    for (int i = 0; i < 8; ++i) {
      float s = sc[(size_t)g * N + n0 + nc * 8 + i];
      float v = ((float)(int)((w >> (4 * i)) & 0xFu) -
                 (float)(int)((z >> (4 * i)) & 0xFu)) * s;
      st[nc * 8 + i][k] = f2bf(v);
    }
  }
  __syncthreads();
  const int n = t >> 2, c = t & 3;
  uint4 v0 = *(const uint4*)&st[n][c * 16];
  uint4 v1 = *(const uint4*)&st[n][c * 16 + 8];
  unsigned short* dst = wt + (size_t)(n0 + n) * K + k0 + c * 16;
  *(uint4*)dst = v0;
  *(uint4*)(dst + 8) = v1;
}

// ---------------- kernel 3: 256x256 8-phase GEMM  C = A[M][K] * B^T([N][K]) ----
// 512 threads = 8 waves (2 M x 4 N), per-wave out 128x64 (acc[8][4] of 16x16).
// LDS: A,B rings of 4 K-slabs (256 rows x 32 k bf16 = 16KB each) = 128 KiB.
// Counted vmcnt(4) only at K-tile boundaries; never 0 until the tail.
// Swizzle: 16B slot ^= (row>>1)&3 on BOTH pre-swizzled global source and
// ds_read address (rule #21).
// Raster: bijective XCD chunking + grouped-m (GM=16, m-fastest) so concurrent
// blocks share A/B K-windows in L2/L3 (R2 post-mortem: naive chunking tripled
// FETCH and made the kernel HBM-bound).

#define STAGE_A(h) do { const unsigned short* g_ = A + gsA + (size_t)(h) * 32;               \
  __builtin_amdgcn_global_load_lds((const __attribute__((address_space(1))) void*)g_,        \
      (__attribute__((address_space(3))) void*)(&sA[(h) & 3][0] + tid * 8), 16, 0, 0);       \
  __builtin_amdgcn_global_load_lds((const __attribute__((address_space(1))) void*)(g_ + (size_t)128 * K), \
      (__attribute__((address_space(3))) void*)(&sA[(h) & 3][4096] + tid * 8), 16, 0, 0); } while (0)
#define STAGE_B(h) do { const unsigned short* g_ = B + gsB + (size_t)(h) * 32;               \
  __builtin_amdgcn_global_load_lds((const __attribute__((address_space(1))) void*)g_,        \
      (__attribute__((address_space(3))) void*)(&sB[(h) & 3][0] + tid * 8), 16, 0, 0);       \
  __builtin_amdgcn_global_load_lds((const __attribute__((address_space(1))) void*)(g_ + (size_t)128 * K), \
      (__attribute__((address_space(3))) void*)(&sB[(h) & 3][4096] + tid * 8), 16, 0, 0); } while (0)

#define LDA(s, m) (*(const bf16x8*)((const char*)&sA[s][0] + offA + (m) * 1024))
#define LDB(s, n) (*(const bf16x8*)((const char*)&sB[s][0] + offB + (n) * 1024))

template <int GELU>
__global__ __launch_bounds__(512, 2) void k_gemm256(const unsigned short* __restrict__ A,
                                                    const unsigned short* __restrict__ B,
                                                    void* __restrict__ C,
                                                    int M, int N, int K) {
  __shared__ __align__(16) unsigned short sA[4][8192];
  __shared__ __align__(16) unsigned short sB[4][8192];
  const int tid = threadIdx.x;
  const int lane = tid & 63;
  const int wave = tid >> 6;
  const int wm = wave >> 2, wn = wave & 3;
  const int r16 = lane & 15, q = lane >> 4;

  // Raster: bijective XCD chunk + grouped-m (GM=16, m-fastest within group).
  const int nbx = N >> 8;
  const int cpx = gridDim.x >> 3;
  const int g = (blockIdx.x & 7) * cpx + (blockIdx.x >> 3);
  const int gw = nbx << 4;                 // blocks per group (pow2 here)
  const int grp = g / gw;
  const int rem = g - grp * gw;
  const int m0 = (grp * 16 + (rem & 15)) * 256;
  const int n0 = (rem >> 4) * 256;

  const int rA = wm * 128 + r16;
  const int rB = wn * 64 + r16;
  const int offA = rA * 64 + ((q * 16) ^ (((rA >> 1) & 3) << 4));
  const int offB = rB * 64 + ((q * 16) ^ (((rB >> 1) & 3) << 4));

  const int sr = tid >> 2;                        // staging row (0..127)
  const int ssrc = (tid & 3) ^ ((sr >> 1) & 3);   // pre-swizzled global 16B slot
  const size_t gsA = (size_t)(m0 + sr) * K + (size_t)ssrc * 8;
  const size_t gsB = (size_t)(n0 + sr) * K + (size_t)ssrc * 8;

  f32x4 acc[8][4] = {};
  const int NT = K >> 6;

  // prologue: slabs 0,1,2 (A+B); guarantee 0,1 resident, slab 2 in flight
  STAGE_A(0); STAGE_B(0); STAGE_A(1); STAGE_B(1); STAGE_A(2); STAGE_B(2);
  asm volatile("s_waitcnt vmcnt(4)" ::: "memory");
  __builtin_amdgcn_s_barrier();

  for (int t = 0; t < NT; ++t) {
    const int s0 = (2 * t) & 3, s1 = (2 * t + 1) & 3;
    const int h3 = 2 * t + 3, h4 = 2 * t + 4;
    bf16x8 af[4], bf[4];

    // ---- phase 1: kk0, m0-3 (8 ds_reads) ; stage A(2t+3)
#pragma unroll
    for (int i = 0; i < 4; ++i) af[i] = LDA(s0, i);
#pragma unroll
    for (int j = 0; j < 4; ++j) bf[j] = LDB(s0, j);
    if (h3 < 2 * NT) STAGE_A(h3);
    __builtin_amdgcn_s_barrier();
    __builtin_amdgcn_s_setprio(1);
#pragma unroll
    for (int i = 0; i < 4; ++i)
#pragma unroll
      for (int j = 0; j < 4; ++j)
        acc[i][j] = __builtin_amdgcn_mfma_f32_16x16x32_bf16(af[i], bf[j], acc[i][j], 0, 0, 0);
    __builtin_amdgcn_s_setprio(0);
    __builtin_amdgcn_s_barrier();

    // ---- phase 2: kk0, m4-7 (4 ds_reads, B reused) ; stage B(2t+3)
#pragma unroll
    for (int i = 0; i < 4; ++i) af[i] = LDA(s0, 4 + i);
    if (h3 < 2 * NT) STAGE_B(h3);
    __builtin_amdgcn_s_barrier();
    __builtin_amdgcn_s_setprio(1);
#pragma unroll
    for (int i = 0; i < 4; ++i)
#pragma unroll
      for (int j = 0; j < 4; ++j)
        acc[4 + i][j] = __builtin_amdgcn_mfma_f32_16x16x32_bf16(af[i], bf[j], acc[4 + i][j], 0, 0, 0);
    __builtin_amdgcn_s_setprio(0);
    __builtin_amdgcn_s_barrier();

    // ---- phase 3: kk1, m0-3 (8 ds_reads) ; stage A(2t+4)
#pragma unroll
    for (int i = 0; i < 4; ++i) af[i] = LDA(s1, i);
#pragma unroll
    for (int j = 0; j < 4; ++j) bf[j] = LDB(s1, j);
    if (h4 < 2 * NT) STAGE_A(h4);
    __builtin_amdgcn_s_barrier();
    __builtin_amdgcn_s_setprio(1);
#pragma unroll
    for (int i = 0; i < 4; ++i)
#pragma unroll
      for (int j = 0; j < 4; ++j)
        acc[i][j] = __builtin_amdgcn_mfma_f32_16x16x32_bf16(af[i], bf[j], acc[i][j], 0, 0, 0);
    __builtin_amdgcn_s_setprio(0);
    __builtin_amdgcn_s_barrier();

    // ---- phase 4: kk1, m4-7 (4 ds_reads) ; stage B(2t+4) ; boundary vmcnt
#pragma unroll
    for (int i = 0; i < 4; ++i) af[i] = LDA(s1, 4 + i);
    if (h4 < 2 * NT) STAGE_B(h4);
    __builtin_amdgcn_s_barrier();
    __builtin_amdgcn_s_setprio(1);
#pragma unroll
    for (int i = 0; i < 4; ++i)
#pragma unroll
      for (int j = 0; j < 4; ++j)
        acc[4 + i][j] = __builtin_amdgcn_mfma_f32_16x16x32_bf16(af[i], bf[j], acc[4 + i][j], 0, 0, 0);
    __builtin_amdgcn_s_setprio(0);
    if (t < NT - 2) { asm volatile("s_waitcnt vmcnt(4)" ::: "memory"); }
    else            { asm volatile("s_waitcnt vmcnt(0)" ::: "memory"); }
    __builtin_amdgcn_s_barrier();
  }

  // epilogue: C/D layout col=lane&15, row=(lane>>4)*4+reg
  const int mb = m0 + wm * 128 + q * 4;
  const int nb = n0 + wn * 64 + r16;
#pragma unroll
  for (int i = 0; i < 8; ++i) {
#pragma unroll
    for (int j = 0; j < 4; ++j) {
#pragma unroll
      for (int r = 0; r < 4; ++r) {
        int row = mb + i * 16 + r;
        int col = nb + j * 16;
        float v = acc[i][j][r];
        if (GELU) {
          v = 0.5f * v * (1.0f + erff(v * 0.70710678118654752440f));
          ((unsigned short*)C)[(size_t)row * N + col] = f2bf(v);
        } else {
          ((float*)C)[(size_t)row * N + col] = v;
        }
      }
    }
  }
}

extern "C" void kernel_launch(void* const* d_in, const int* in_sizes, int n_in,
                              void* d_out, int out_size, void* d_ws, size_t ws_size,
                              hipStream_t stream) {
  const float* x  = (const float*)d_in[0];
  const int* uqw  = (const int*)d_in[1];
  const int* uqz  = (const int*)d_in[2];
  const float* usc = (const float*)d_in[3];
  const int* dqw  = (const int*)d_in[4];
  const int* dqz  = (const int*)d_in[5];
  const float* dsc = (const float*)d_in[6];
  float* out = (float*)d_out;

  const int T = 8192, D = 4096, F = 16384;
  char* ws = (char*)d_ws;
  unsigned short* xb = (unsigned short*)ws;                                  // 64 MiB
  unsigned short* h  = (unsigned short*)(ws + (size_t)T * D * 2);            // 256 MiB
  unsigned short* wt = (unsigned short*)(ws + (size_t)T * D * 2 + (size_t)T * F * 2); // 128 MiB

  k_f32_to_bf16<<<dim3((T * D) / (256 * 8)), 256, 0, stream>>>(x, xb);
  k_dequant_t<<<dim3(D / 64, F / 64), 256, 0, stream>>>(uqw, uqz, usc, wt, D, F);
  k_gemm256<1><<<dim3((T / 256) * (F / 256)), 512, 0, stream>>>(xb, wt, (void*)h, T, F, D);
  k_dequant_t<<<dim3(F / 64, D / 64), 256, 0, stream>>>(dqw, dqz, dsc, wt, F, D);
  k_gemm256<0><<<dim3((T / 256) * (D / 256)), 512, 0, stream>>>(h, wt, (void*)out, T, D, F);
}